// Round 3
// baseline (684.318 us; speedup 1.0000x reference)
//
#include <hip/hip_runtime.h>

// Cost-volume construction, out (B=2, 2C=64, D=64, H=80, W=240) fp32 = 629 MB.
//   out[b][c   ][d][h][w] = x[b][c][h][w]   * (w>=d)
//   out[b][32+c][d][h][w] = y[b][c][h][w-d] * (w>=d)
//
// One block per OUTPUT SLICE (b,ch,d) = contiguous 76.8 KB  =>  the store
// stream is fully sequential (4 KB per 256-thread iteration), matching the
// DRAM page locality that lets fillBuffer hit 6.2 TB/s; the previous
// row-per-block layout emitted scattered 960 B bursts (~2.9 TB/s).
//  - d is BLOCK-uniform: left mask and the right-half shift (d&3) are scalar.
//  - right half: aligned-quad splice of y[h][qw-k-1], y[h][qw-k]; quad
//    boundaries align exactly with the w<d zero region, so zero-extension at
//    quad granularity is exact (quad q holds y-indices 4q..4q+3, same sign).
//  - no LDS, no __syncthreads: reads served from L2/L3 (x+y = 39 MB resident).
//  - XCD-bijective swizzle: all 64 d-blocks of one (b,ch) plane land on one
//    XCD so each input plane is fetched into ONE L2 (HBM re-fetch 8x -> 1x).
// Output stores nontemporal (write-once, never re-read).

#define NQP  4800u      // H*W4 = 80*60 float4 per input plane / per output slice
#define W4q  60u        // float4 per row (W=240)

typedef float f32x4 __attribute__((ext_vector_type(4)));

__device__ __forceinline__ void nt_store4(float4 v, float4* p) {
    f32x4 t; t.x = v.x; t.y = v.y; t.z = v.z; t.w = v.w;
    __builtin_nontemporal_store(t, reinterpret_cast<f32x4*>(p));
}

template <int SH>   // start offset inside quad a; result = floats a[SH..], b[0..]
__device__ __forceinline__ float4 splice(float4 a, float4 b) {
    if constexpr (SH == 1)      return make_float4(a.y, a.z, a.w, b.x);
    else if constexpr (SH == 2) return make_float4(a.z, a.w, b.x, b.y);
    else                        return make_float4(a.w, b.x, b.y, b.z);
}

template <int SH>   // SH = 0 (d%4==0) or 4-(d&3)
__device__ __forceinline__ void right_path(const float4* __restrict__ src4,
                                           float4* __restrict__ dst4,
                                           unsigned t, unsigned k) {
    const float4 zero = make_float4(0.f, 0.f, 0.f, 0.f);
    for (unsigned i = t; i < NQP; i += 256u) {
        const unsigned h  = i / W4q;
        const unsigned qw = i - h * W4q;
        const float4* row = src4 + h * W4q;
        const int qb = (int)qw - (int)k;          // aligned source quad
        float4 vb = (qb >= 0) ? row[qb] : zero;
        float4 v;
        if constexpr (SH == 0) {
            v = vb;
        } else {
            const int qa = qb - 1;
            float4 va = (qa >= 0) ? row[qa] : zero;
            v = splice<SH>(va, vb);
        }
        nt_store4(v, &dst4[i]);
    }
}

__global__ __launch_bounds__(256) void costvol_kernel(const float* __restrict__ x,
                                                      const float* __restrict__ y,
                                                      float* __restrict__ out) {
    // XCD-bijective swizzle: blk = ((p>>3)*64 + d)*8 + (p&7),  p = b*64+ch.
    const unsigned blk  = blockIdx.x;             // [0, 8192)
    const unsigned xcd  = blk & 7u;
    const unsigned rest = blk >> 3;               // (p>>3)*64 + d
    const unsigned d    = rest & 63u;
    const unsigned p    = (rest >> 6) * 8u + xcd; // b*64 + ch, [0,128)
    const unsigned ch   = p & 63u;
    const unsigned b    = p >> 6;
    const unsigned c    = ch & 31u;
    const bool right    = ch >= 32u;

    const float4* src4 = (const float4*)(right ? y : x) + (size_t)(b * 32u + c) * NQP;
    float4*       dst4 = (float4*)out + (size_t)(p * 64u + d) * NQP;

    const unsigned t = threadIdx.x;

    if (!right) {
        // ---- Left: copy x-plane, zero columns w < d (d block-uniform). ----
        const int dd = (int)d;
        for (unsigned i = t; i < NQP; i += 256u) {
            const unsigned h  = i / W4q;
            const unsigned qw = i - h * W4q;
            float4 v = src4[i];
            const int w0 = 4 * (int)qw;
            if (w0 + 0 < dd) v.x = 0.f;
            if (w0 + 1 < dd) v.y = 0.f;
            if (w0 + 2 < dd) v.z = 0.f;
            if (w0 + 3 < dd) v.w = 0.f;
            nt_store4(v, &dst4[i]);
        }
    } else {
        // ---- Right: shifted y-plane; shift mod 4 is block-uniform. ----
        const unsigned k = d >> 2;
        switch (d & 3u) {
            case 0:  right_path<0>(src4, dst4, t, k); break;
            case 1:  right_path<3>(src4, dst4, t, k); break;
            case 2:  right_path<2>(src4, dst4, t, k); break;
            default: right_path<1>(src4, dst4, t, k); break;
        }
    }
}

extern "C" void kernel_launch(void* const* d_in, const int* in_sizes, int n_in,
                              void* d_out, int out_size, void* d_ws, size_t ws_size,
                              hipStream_t stream) {
    const float* x = (const float*)d_in[0];
    const float* y = (const float*)d_in[1];
    float* out     = (float*)d_out;

    dim3 grid(2u * 64u * 64u), block(256);   // one block per (b,ch,d) output slice
    hipLaunchKernelGGL(costvol_kernel, grid, block, 0, stream, x, y, out);
}